// Round 2
// baseline (149.308 us; speedup 1.0000x reference)
//
#include <hip/hip_runtime.h>

// Projector: out[b,k,d] = sum_l softmax_k( cos(p_k, x[b,l]) ) * x[b,l,d]
// B=4096, L=200, D=64, K=8, fp32. HBM-bound target ~35us.
// Single pass: x staged tile-wise; dots computed from registers during staging
// (no LDS re-read); cross-chunk score reduce via DPP (VALU pipe, not LDS);
// accumulate reads tile once per k-half with all-b128 LDS ops.

#define LQ 200
#define DQ 64
#define KQ 8
#define TR 64
#define XS 68          // xt row stride in floats: 272 B = 17*16 -> b128-aligned rows
#define NT 4           // ceil(200/64): tiles of 64,64,64,8 rows

__device__ __forceinline__ float dot4f(float4 a, float4 b) {
    return a.x * b.x + a.y * b.y + a.z * b.z + a.w * b.w;
}
// quad_perm [1,0,3,2] = xor-1 within quads; [2,3,0,1] = xor-2. VALU-pipe crosslane.
__device__ __forceinline__ float dpp_swap1(float v) {
    return __int_as_float(__builtin_amdgcn_update_dpp(
        0, __float_as_int(v), 0xB1, 0xF, 0xF, true));
}
__device__ __forceinline__ float dpp_add1(float v) { return v + dpp_swap1(v); }
__device__ __forceinline__ float dpp_add2(float v) {
    return v + __int_as_float(__builtin_amdgcn_update_dpp(
        0, __float_as_int(v), 0x4E, 0xF, 0xF, true));
}

__global__ __launch_bounds__(64) void proto_norm_kernel(const float* __restrict__ proto,
                                                        float* __restrict__ pn) {
    const int lane = threadIdx.x;  // d
    for (int k = 0; k < KQ; ++k) {
        float v = proto[k * DQ + lane];
        float sq = v * v;
        #pragma unroll
        for (int off = 32; off > 0; off >>= 1) sq += __shfl_xor(sq, off, 64);
        pn[k * DQ + lane] = v * __frsqrt_rn(fmaxf(sq, 1e-12f));
    }
}

__global__ __launch_bounds__(256) void projector_kernel(const float* __restrict__ x,
                                                        const float* __restrict__ pn,
                                                        float* __restrict__ out) {
    __shared__ __align__(16) float xt[TR * XS];   // 17408 B
    __shared__ __align__(16) float sA[TR * KQ];   // attn [row][k], 2048 B

    const int b = blockIdx.x;
    const int t = threadIdx.x;
    const int lane = t & 63;
    const int w = __builtin_amdgcn_readfirstlane(t >> 6);

    // stage/dot mapping: thread owns row = t>>2, 16-float chunk c = t&3
    const int srow = t >> 2;
    const int sc   = t & 3;
    const int codd = sc & 1;
    const int chi  = (sc >> 1) & 1;
    const int kp0  = (codd << 2) | (sc & 2);   // this lane's k-pair after reduce

    // accumulate mapping: thread owns (d-quad aq, row-group ag, k-half ah)
    const int aq = (lane & 7) | ((w & 1) << 3);  // 0..15
    const int ag = lane >> 3;                     // 0..7 (8 rows each)
    const int ah = w >> 1;                        // 0..1 (k 4h..4h+3)

    const float* xb = x + (size_t)b * (LQ * DQ);

    float4 px0, px1, px2, px3;   // this thread's 16 staged floats (prefetched)
    {
        const float4* p = (const float4*)(xb + srow * DQ + sc * 16);
        px0 = p[0]; px1 = p[1]; px2 = p[2]; px3 = p[3];
    }

    float4 acc0 = make_float4(0.f, 0.f, 0.f, 0.f);
    float4 acc1 = acc0, acc2 = acc0, acc3 = acc0;

    #pragma unroll
    for (int ti = 0; ti < NT; ++ti) {
        const int nr = (ti == NT - 1) ? (LQ - (NT - 1) * TR) : TR;  // compile-time

        // ---------------- phase 1: dots from regs, stage, softmax ----------------
        float sq = dot4f(px0, px0) + dot4f(px1, px1) + dot4f(px2, px2) + dot4f(px3, px3);

        float s[KQ];
        #pragma unroll
        for (int k = 0; k < KQ; ++k) {
            int kk = k;
            asm volatile("" : "+s"(kk));   // opaque: stop hoisting 128 p-hat floats to VGPRs
            const float4* pk = (const float4*)(pn + kk * DQ + sc * 16);
            float4 a = pk[0], b4 = pk[1], c4 = pk[2], d4 = pk[3];
            s[k] = dot4f(px0, a) + dot4f(px1, b4) + dot4f(px2, c4) + dot4f(px3, d4);
        }

        {   // stage to LDS (b128 x4, 16B-aligned rows)
            float4* dst = (float4*)&xt[srow * XS + sc * 16];
            dst[0] = px0; dst[1] = px1; dst[2] = px2; dst[3] = px3;
        }

        // quad reduce with k-split: evens end with S[0..3], odds with S[4..7]
        float r0, r1, r2, r3;
        {
            float u0 = codd ? s[0] : s[4];
            float u1 = codd ? s[1] : s[5];
            float u2 = codd ? s[2] : s[6];
            float u3 = codd ? s[3] : s[7];
            float k0 = codd ? s[4] : s[0];
            float k1 = codd ? s[5] : s[1];
            float k2 = codd ? s[6] : s[2];
            float k3 = codd ? s[7] : s[3];
            r0 = k0 + dpp_swap1(u0);
            r1 = k1 + dpp_swap1(u1);
            r2 = k2 + dpp_swap1(u2);
            r3 = k3 + dpp_swap1(u3);
        }
        r0 = dpp_add2(r0); r1 = dpp_add2(r1); r2 = dpp_add2(r2); r3 = dpp_add2(r3);
        sq = dpp_add2(dpp_add1(sq));

        // softmax over K (cos in [-1,1]: no max-subtract needed)
        float rn = __frsqrt_rn(fmaxf(sq, 1e-12f));
        float ta = chi ? r2 : r0;
        float tb = chi ? r3 : r1;
        float e0 = __expf(ta * rn);
        float e1 = __expf(tb * rn);
        float es = dpp_add2(dpp_add1(e0 + e1));
        float rd = __frcp_rn(es);
        *(float2*)&sA[srow * KQ + kp0] = make_float2(e0 * rd, e1 * rd);
        // rows >= nr (last tile) hold stale-but-finite junk; accumulate guards them.

        __syncthreads();

        // ---------------- phase 2: prefetch next tile, accumulate ----------------
        if (ti + 1 < NT) {
            const int nrn = (ti + 1 == NT - 1) ? (LQ - (NT - 1) * TR) : TR;
            if (srow < nrn) {
                const float4* p = (const float4*)(xb + ((ti + 1) * TR + srow) * DQ + sc * 16);
                px0 = p[0]; px1 = p[1]; px2 = p[2]; px3 = p[3];
            }
        }

        if (nr == TR) {
            #pragma unroll
            for (int r = 0; r < 8; ++r) {
                const int row = ag * 8 + r;
                float4 av = *(const float4*)&sA[row * KQ + ah * 4];
                float4 xv = *(const float4*)&xt[row * XS + aq * 4];
                acc0.x += av.x * xv.x; acc0.y += av.x * xv.y; acc0.z += av.x * xv.z; acc0.w += av.x * xv.w;
                acc1.x += av.y * xv.x; acc1.y += av.y * xv.y; acc1.z += av.y * xv.z; acc1.w += av.y * xv.w;
                acc2.x += av.z * xv.x; acc2.y += av.z * xv.y; acc2.z += av.z * xv.z; acc2.w += av.z * xv.w;
                acc3.x += av.w * xv.x; acc3.y += av.w * xv.y; acc3.z += av.w * xv.z; acc3.w += av.w * xv.w;
            }
        } else {
            #pragma unroll
            for (int r = 0; r < 8; ++r) {
                const int row = ag * 8 + r;
                if (row < nr) {
                    float4 av = *(const float4*)&sA[row * KQ + ah * 4];
                    float4 xv = *(const float4*)&xt[row * XS + aq * 4];
                    acc0.x += av.x * xv.x; acc0.y += av.x * xv.y; acc0.z += av.x * xv.z; acc0.w += av.x * xv.w;
                    acc1.x += av.y * xv.x; acc1.y += av.y * xv.y; acc1.z += av.y * xv.z; acc1.w += av.y * xv.w;
                    acc2.x += av.z * xv.x; acc2.y += av.z * xv.y; acc2.z += av.z * xv.z; acc2.w += av.z * xv.w;
                    acc3.x += av.w * xv.x; acc3.y += av.w * xv.y; acc3.z += av.w * xv.z; acc3.w += av.w * xv.w;
                }
            }
        }
        __syncthreads();
    }

    // ---------------- final: reduce partials over row-groups (reuse xt) ----------------
    {
        float* red = xt;  // layout [k(8)][g(8)][q(16)][d(4)] floats = 16 KB, fits in xt
        const int kb = ah * 4;
        const int base = ag * 64 + aq * 4;
        *(float4*)&red[(kb + 0) * 512 + base] = acc0;
        *(float4*)&red[(kb + 1) * 512 + base] = acc1;
        *(float4*)&red[(kb + 2) * 512 + base] = acc2;
        *(float4*)&red[(kb + 3) * 512 + base] = acc3;
        __syncthreads();
        if (t < 128) {
            const int k = t >> 4;
            const int q = t & 15;
            float4 sum = make_float4(0.f, 0.f, 0.f, 0.f);
            #pragma unroll
            for (int g = 0; g < 8; ++g) {
                float4 v = *(const float4*)&red[k * 512 + g * 64 + q * 4];
                sum.x += v.x; sum.y += v.y; sum.z += v.z; sum.w += v.w;
            }
            *(float4*)(out + (size_t)b * (KQ * DQ) + k * DQ + q * 4) = sum;
        }
    }
}

extern "C" void kernel_launch(void* const* d_in, const int* in_sizes, int n_in,
                              void* d_out, int out_size, void* d_ws, size_t ws_size,
                              hipStream_t stream) {
    const float* x     = (const float*)d_in[0];   // [B, L, D] fp32
    const float* proto = (const float*)d_in[1];   // [K, D] fp32
    float* out = (float*)d_out;                   // [B, K, D] fp32
    float* pn  = (float*)d_ws;                    // normalized prototype (2 KB)

    const int Bn = in_sizes[0] / (LQ * DQ);       // 4096

    proto_norm_kernel<<<1, 64, 0, stream>>>(proto, pn);
    projector_kernel<<<Bn, 256, 0, stream>>>(x, pn, out);
}

// Round 3
// 109.104 us; speedup vs baseline: 1.3685x; 1.3685x over previous
//
#include <hip/hip_runtime.h>

// Projector: out[b,k,d] = sum_l softmax_k( cos(p_k, x[b,l]) ) * x[b,l,d]
// B=4096, L=200, D=64, K=8, fp32. HBM roofline ~35us.
// v3: dots entirely from registers (p-hat hoisted: 8k x 8-float chunk = 64 VGPR),
// split-butterfly reduce (DPP + one ds_swizzle), in-register softmax,
// bank-conflict-proof LDS layouts, prefetched staging.

#define LQ 200
#define DQ 64
#define KQ 8
#define TR 64
#define NT 4

#define XT_SZ 4376   // xt: XROW(63)+63 = 4375
#define SA_SZ 792    // sA: SROW(63)+7  = 791

// row offsets in dwords; the +4*(r>>3) bump breaks the (stride*8 % 32 == 0)
// bank-aliasing period that caused R2's 6.8M conflicts.
__device__ __forceinline__ int XROW(int r) { return r * 68 + ((r >> 3) << 2); }
__device__ __forceinline__ int SROW(int r) { return r * 12 + ((r >> 3) << 2); }

__device__ __forceinline__ float dppx1(float v) {   // lane ^ 1 (quad_perm [1,0,3,2])
    return __int_as_float(__builtin_amdgcn_update_dpp(0, __float_as_int(v), 0xB1, 0xF, 0xF, true));
}
__device__ __forceinline__ float dppx2(float v) {   // lane ^ 2 (quad_perm [2,3,0,1])
    return __int_as_float(__builtin_amdgcn_update_dpp(0, __float_as_int(v), 0x4E, 0xF, 0xF, true));
}
__device__ __forceinline__ float swz4(float v) {    // lane ^ 4 (ds_swizzle BitMode xor=4)
    return __int_as_float(__builtin_amdgcn_ds_swizzle(__float_as_int(v), 0x101F));
}
__device__ __forceinline__ float allred8(float v) { // all-reduce over lanes (t&7)
    v += dppx1(v); v += dppx2(v); v += swz4(v); return v;
}
__device__ __forceinline__ float dot4f(float4 a, float4 b) {
    return a.x * b.x + a.y * b.y + a.z * b.z + a.w * b.w;
}

// split butterfly over the 8 chunk-lanes: input s[8] = partial dots (this lane's
// 8-float chunk, all 8 k). Output: full dot for k == (t&7) on this lane.
__device__ __forceinline__ float reduce_dots(const float* s, bool b1, bool b2, bool b3) {
    float T0 = (b1 ? s[1] : s[0]) + dppx1(b1 ? s[0] : s[1]);
    float T1 = (b1 ? s[3] : s[2]) + dppx1(b1 ? s[2] : s[3]);
    float T2 = (b1 ? s[5] : s[4]) + dppx1(b1 ? s[4] : s[5]);
    float T3 = (b1 ? s[7] : s[6]) + dppx1(b1 ? s[6] : s[7]);
    float K0 = (b2 ? T1 : T0) + dppx2(b2 ? T0 : T1);
    float K1 = (b2 ? T3 : T2) + dppx2(b2 ? T2 : T3);
    return (b3 ? K1 : K0) + swz4(b3 ? K0 : K1);
}

__global__ __launch_bounds__(64) void proto_norm_kernel(const float* __restrict__ proto,
                                                        float* __restrict__ pn) {
    const int lane = threadIdx.x;
    for (int k = 0; k < KQ; ++k) {
        float v = proto[k * DQ + lane];
        float sq = v * v;
        #pragma unroll
        for (int off = 32; off > 0; off >>= 1) sq += __shfl_xor(sq, off, 64);
        pn[k * DQ + lane] = v * __frsqrt_rn(fmaxf(sq, 1e-12f));
    }
}

__global__ __launch_bounds__(256) void projector_kernel(const float* __restrict__ x,
                                                        const float* __restrict__ pn,
                                                        float* __restrict__ out) {
    __shared__ __align__(16) float xt[XT_SZ];
    __shared__ __align__(16) float sA[SA_SZ];

    const int b  = blockIdx.x;
    const int t  = threadIdx.x;
    const int w  = t >> 6;
    const int c  = t & 7;           // 8-float chunk id; also this lane's k after reduce
    const int rp = t >> 3;          // row-pair 0..31 -> rows 2rp, 2rp+1
    const bool b1 = (c & 1) != 0;
    const bool b2 = (c & 2) != 0;
    const bool b3 = (c & 4) != 0;

    // accumulate mapping: k-half ah, row-group ag, XOR-swizzled d-quad aqe
    const int ah  = w >> 1;
    const int ag  = (t >> 3) & 7;
    const int aqe = ((t & 7) ^ ag) | ((w & 1) << 3);

    const float* xb = x + (size_t)b * (LQ * DQ);

    // p-hat in registers: 8 k x this lane's 8-float chunk (64 VGPR, loaded once)
    float4 phA[KQ], phB[KQ];
    #pragma unroll
    for (int k = 0; k < KQ; ++k) {
        const float4* p = (const float4*)(pn + k * DQ + c * 8);
        phA[k] = p[0]; phB[k] = p[1];
    }

    const int r0 = 2 * rp, r1 = 2 * rp + 1;

    float4 xA0, xB0, xA1, xB1;      // this thread's staged 16 floats (2 rows x 8)
    {
        const float4* p0 = (const float4*)(xb + r0 * DQ + c * 8);
        const float4* p1 = (const float4*)(xb + r1 * DQ + c * 8);
        xA0 = p0[0]; xB0 = p0[1]; xA1 = p1[0]; xB1 = p1[1];
    }

    float4 acc0 = make_float4(0.f, 0.f, 0.f, 0.f);
    float4 acc1 = acc0, acc2 = acc0, acc3 = acc0;

    #pragma unroll
    for (int ti = 0; ti < NT; ++ti) {
        const int nr = (ti == NT - 1) ? (LQ - (NT - 1) * TR) : TR;

        // ---- stage px -> LDS (b128 writes, <=2-way banks)
        {
            float4* d0 = (float4*)&xt[XROW(r0) + c * 8];
            d0[0] = xA0; d0[1] = xB0;
            float4* d1 = (float4*)&xt[XROW(r1) + c * 8];
            d1[0] = xA1; d1[1] = xB1;
        }

        // ---- prefetch next tile into regs (hidden under dots + accumulate)
        float4 nA0 = xA0, nB0 = xB0, nA1 = xA1, nB1 = xB1;  // keep-stale default
        if (ti + 1 < NT) {
            const int nrn = (ti + 1 == NT - 1) ? (LQ - (NT - 1) * TR) : TR;
            if (r0 < nrn) {  // nrn even -> covers r1 too
                const float4* p0 = (const float4*)(xb + ((ti + 1) * TR + r0) * DQ + c * 8);
                const float4* p1 = (const float4*)(xb + ((ti + 1) * TR + r1) * DQ + c * 8);
                nA0 = p0[0]; nB0 = p0[1]; nA1 = p1[0]; nB1 = p1[1];
            }
        }

        // ---- dots: registers only
        float s0[KQ], s1[KQ];
        #pragma unroll
        for (int k = 0; k < KQ; ++k) {
            s0[k] = dot4f(xA0, phA[k]) + dot4f(xB0, phB[k]);
            s1[k] = dot4f(xA1, phA[k]) + dot4f(xB1, phB[k]);
        }
        float sq0 = allred8(dot4f(xA0, xA0) + dot4f(xB0, xB0));
        float sq1 = allred8(dot4f(xA1, xA1) + dot4f(xB1, xB1));

        float d0v = reduce_dots(s0, b1, b2, b3);   // full dot(row0, k=c)
        float d1v = reduce_dots(s1, b1, b2, b3);

        // ---- softmax over k fully in registers (|cos|<=1: no max-subtract)
        float rn0 = __frsqrt_rn(fmaxf(sq0, 1e-12f));
        float rn1 = __frsqrt_rn(fmaxf(sq1, 1e-12f));
        float e0 = __expf(d0v * rn0);
        float e1 = __expf(d1v * rn1);
        float a0 = e0 * __frcp_rn(allred8(e0));
        float a1 = e1 * __frcp_rn(allred8(e1));
        sA[SROW(r0) + c] = a0;
        sA[SROW(r1) + c] = a1;
        // last tile, rows >= nr: stale-but-finite (cos<=1 by construction); never consumed.

        __syncthreads();

        // ---- accumulate: acc[k=4ah+i][d-quad aqe] += attn[row][k] * x[row][d]
        if (nr == TR) {
            #pragma unroll
            for (int r = 0; r < 8; ++r) {
                const int row = ag * 8 + r;
                float4 av = *(const float4*)&sA[SROW(row) + 4 * ah];   // broadcast
                float4 xv = *(const float4*)&xt[XROW(row) + 4 * aqe];  // conflict-free
                acc0.x += av.x * xv.x; acc0.y += av.x * xv.y; acc0.z += av.x * xv.z; acc0.w += av.x * xv.w;
                acc1.x += av.y * xv.x; acc1.y += av.y * xv.y; acc1.z += av.y * xv.z; acc1.w += av.y * xv.w;
                acc2.x += av.z * xv.x; acc2.y += av.z * xv.y; acc2.z += av.z * xv.z; acc2.w += av.z * xv.w;
                acc3.x += av.w * xv.x; acc3.y += av.w * xv.y; acc3.z += av.w * xv.z; acc3.w += av.w * xv.w;
            }
        } else {
            #pragma unroll
            for (int r = 0; r < 8; ++r) {
                const int row = ag * 8 + r;
                if (row < nr) {
                    float4 av = *(const float4*)&sA[SROW(row) + 4 * ah];
                    float4 xv = *(const float4*)&xt[XROW(row) + 4 * aqe];
                    acc0.x += av.x * xv.x; acc0.y += av.x * xv.y; acc0.z += av.x * xv.z; acc0.w += av.x * xv.w;
                    acc1.x += av.y * xv.x; acc1.y += av.y * xv.y; acc1.z += av.y * xv.z; acc1.w += av.y * xv.w;
                    acc2.x += av.z * xv.x; acc2.y += av.z * xv.y; acc2.z += av.z * xv.z; acc2.w += av.z * xv.w;
                    acc3.x += av.w * xv.x; acc3.y += av.w * xv.y; acc3.z += av.w * xv.z; acc3.w += av.w * xv.w;
                }
            }
        }
        __syncthreads();

        xA0 = nA0; xB0 = nB0; xA1 = nA1; xB1 = nB1;
    }

    // ---- final: reduce partials over the 8 row-groups (reuse xt as [k][g][q][4])
    {
        const int kb = ah * 4;
        #pragma unroll
        for (int i = 0; i < 4; ++i) {
            float4 v = (i == 0) ? acc0 : (i == 1) ? acc1 : (i == 2) ? acc2 : acc3;
            *(float4*)&xt[(kb + i) * 512 + ag * 64 + aqe * 4] = v;
        }
        __syncthreads();
        if (t < 128) {
            const int k = t >> 4;
            const int q = t & 15;
            float4 sum = make_float4(0.f, 0.f, 0.f, 0.f);
            #pragma unroll
            for (int g = 0; g < 8; ++g) {
                float4 v = *(const float4*)&xt[k * 512 + g * 64 + q * 4];
                sum.x += v.x; sum.y += v.y; sum.z += v.z; sum.w += v.w;
            }
            *(float4*)(out + (size_t)b * (KQ * DQ) + k * DQ + q * 4) = sum;
        }
    }
}

extern "C" void kernel_launch(void* const* d_in, const int* in_sizes, int n_in,
                              void* d_out, int out_size, void* d_ws, size_t ws_size,
                              hipStream_t stream) {
    const float* x     = (const float*)d_in[0];   // [B, L, D] fp32
    const float* proto = (const float*)d_in[1];   // [K, D] fp32
    float* out = (float*)d_out;                   // [B, K, D] fp32
    float* pn  = (float*)d_ws;                    // normalized prototype (2 KB)

    const int Bn = in_sizes[0] / (LQ * DQ);       // 4096

    proto_norm_kernel<<<1, 64, 0, stream>>>(proto, pn);
    projector_kernel<<<Bn, 256, 0, stream>>>(x, pn, out);
}

// Round 4
// 59.567 us; speedup vs baseline: 2.5066x; 1.8316x over previous
//
#include <hip/hip_runtime.h>

// Projector: out[b,k,d] = sum_l softmax_k( cos(p_k, x[b,l]) ) * x[b,l,d]
// B=4096, L=200, D=64, K=8, fp32.
// v4: occupancy-first. 21 KB LDS, launch_bounds(256,4) -> 4 blocks/CU.
// ph1: thread owns quarter-row; dot reduce = 2 DPP adds (lanes of a row are a quad).
// p-hat via LDS broadcast (no 64-VGPR hoard). XOR-swizzled x tile (true conflict-free).
// ph2: k-in-thread (x read exactly once). T14 reg-prefetch of next tile.

#define LQ 200
#define DQ 64
#define KQ 8
#define TR 64
#define NT 4
#define XTQ (TR * 16)   // 1024 quads = 16 KB

// attn row offset (dwords); conflict-free for ph1 write (32-lane, 2 halves) and
// ph2 multicast read (4 distinct rows/instr -> distinct bank-quads, verified).
__device__ __forceinline__ int AROW(int r) { return 100 * (r >> 3) + 12 * (r & 7); }
#define SA_SZ 800

__device__ __forceinline__ float dppx1(float v) {   // lane ^ 1 within quad
    return __int_as_float(__builtin_amdgcn_update_dpp(0, __float_as_int(v), 0xB1, 0xF, 0xF, true));
}
__device__ __forceinline__ float dppx2(float v) {   // lane ^ 2 within quad
    return __int_as_float(__builtin_amdgcn_update_dpp(0, __float_as_int(v), 0x4E, 0xF, 0xF, true));
}
__device__ __forceinline__ float dot4f(float4 a, float4 b) {
    return a.x * b.x + a.y * b.y + a.z * b.z + a.w * b.w;
}
__device__ __forceinline__ void fma4(float4& acc, float a, float4 v) {
    acc.x += a * v.x; acc.y += a * v.y; acc.z += a * v.z; acc.w += a * v.w;
}
__device__ __forceinline__ void add4(float4& acc, float4 v) {
    acc.x += v.x; acc.y += v.y; acc.z += v.z; acc.w += v.w;
}

__global__ __launch_bounds__(64) void proto_norm_kernel(const float* __restrict__ proto,
                                                        float* __restrict__ pn) {
    const int lane = threadIdx.x;
    for (int k = 0; k < KQ; ++k) {
        float v = proto[k * DQ + lane];
        float sq = v * v;
        #pragma unroll
        for (int off = 32; off > 0; off >>= 1) sq += __shfl_xor(sq, off, 64);
        pn[k * DQ + lane] = v * __frsqrt_rn(fmaxf(sq, 1e-12f));
    }
}

__global__ __launch_bounds__(256, 4) void projector_kernel(const float* __restrict__ x,
                                                           const float* __restrict__ pn,
                                                           float* __restrict__ out) {
    __shared__ __align__(16) float4 xt[XTQ];      // 16 KB, XOR-swizzled quads
    __shared__ __align__(16) float4 pd[KQ * 16];  // 2 KB normalized prototype
    __shared__ __align__(16) float  sA[SA_SZ];    // 3.2 KB attn

    const int b = blockIdx.x;
    const int t = threadIdx.x;

    if (t < 128) pd[t] = ((const float4*)pn)[t];  // covered by first barrier

    const int r1 = t >> 2;       // ph1: row 0..63
    const int qt = t & 3;        //      quarter (lanes of a row = one DPP quad)
    const int qd = t & 15;       // ph2: d-quad
    const int rg = t >> 4;       //      row-group 0..15 (4 rows each)

    const float4* xb4 = (const float4*)(x + (size_t)b * (LQ * DQ));

    // tile-0 staged in registers (16 VGPR)
    float4 st0 = xb4[t], st1 = xb4[256 + t], st2 = xb4[512 + t], st3 = xb4[768 + t];

    float4 acc[KQ];
    #pragma unroll
    for (int k = 0; k < KQ; ++k) acc[k] = make_float4(0.f, 0.f, 0.f, 0.f);

    #pragma unroll
    for (int ti = 0; ti < NT; ++ti) {
        const int nr = (ti == NT - 1) ? (LQ - (NT - 1) * TR) : TR;   // compile-time
        const int nq = nr * 16;

        // ---- stage regs -> LDS, physical quad = q ^ (row & 15)
        { int q = t;       if (q < nq) { int r = q >> 4; xt[(r << 4) | ((q & 15) ^ (r & 15))] = st0; } }
        { int q = 256 + t; if (q < nq) { int r = q >> 4; xt[(r << 4) | ((q & 15) ^ (r & 15))] = st1; } }
        { int q = 512 + t; if (q < nq) { int r = q >> 4; xt[(r << 4) | ((q & 15) ^ (r & 15))] = st2; } }
        { int q = 768 + t; if (q < nq) { int r = q >> 4; xt[(r << 4) | ((q & 15) ^ (r & 15))] = st3; } }
        __syncthreads();

        // ---- T14: issue next tile's global loads now; consumed after ph2's barrier
        if (ti + 1 < NT) {
            const int nnq = ((ti + 1 == NT - 1) ? (LQ - (NT - 1) * TR) : TR) * 16;
            const float4* src = xb4 + (ti + 1) * XTQ;
            { int q = t;       if (q < nnq) st0 = src[q]; }
            { int q = 256 + t; if (q < nnq) st1 = src[q]; }
            { int q = 512 + t; if (q < nnq) st2 = src[q]; }
            { int q = 768 + t; if (q < nnq) st3 = src[q]; }
        }

        // ---- phase 1: quarter-row dots, DPP reduce, in-thread softmax
        if (r1 < nr) {
            // stop the compiler hoisting the 32 pd broadcasts out of the tile loop
            unsigned pdo = 0;
            asm volatile("" : "+v"(pdo));
            const float4* pdp = pd + pdo;

            const int rb = r1 << 4;
            const int rx = r1 & 15;
            float4 xq0 = xt[rb | ((4 * qt + 0) ^ rx)];
            float4 xq1 = xt[rb | ((4 * qt + 1) ^ rx)];
            float4 xq2 = xt[rb | ((4 * qt + 2) ^ rx)];
            float4 xq3 = xt[rb | ((4 * qt + 3) ^ rx)];

            float sq = dot4f(xq0, xq0) + dot4f(xq1, xq1) + dot4f(xq2, xq2) + dot4f(xq3, xq3);
            float s[KQ];
            #pragma unroll
            for (int k = 0; k < KQ; ++k) {
                const float4* pk = &pdp[k * 16 + 4 * qt];   // broadcast b128 reads
                s[k] = dot4f(xq0, pk[0]) + dot4f(xq1, pk[1]) +
                       dot4f(xq2, pk[2]) + dot4f(xq3, pk[3]);
            }
            #pragma unroll
            for (int k = 0; k < KQ; ++k) { s[k] += dppx1(s[k]); s[k] += dppx2(s[k]); }
            sq += dppx1(sq); sq += dppx2(sq);

            float rn = __frsqrt_rn(fmaxf(sq, 1e-12f));
            float e[KQ]; float es = 0.f;
            #pragma unroll
            for (int k = 0; k < KQ; ++k) { e[k] = __expf(s[k] * rn); es += e[k]; }
            float rd = __frcp_rn(es);
            if (qt < 2) {   // qt0 writes k0..3, qt1 writes k4..7
                float4 w4 = make_float4(e[4 * qt + 0] * rd, e[4 * qt + 1] * rd,
                                        e[4 * qt + 2] * rd, e[4 * qt + 3] * rd);
                *(float4*)&sA[AROW(r1) + 4 * qt] = w4;
            }
        }
        __syncthreads();

        // ---- phase 2: acc[k] += attn[r][k] * x[r][d-quad]  (x read exactly once)
        #pragma unroll
        for (int i = 0; i < 4; ++i) {
            const int r = rg * 4 + i;
            if (r < nr) {
                float4 xv = xt[(r << 4) | (qd ^ (r & 15))];
                float4 a0 = *(const float4*)&sA[AROW(r)];
                float4 a1 = *(const float4*)&sA[AROW(r) + 4];
                fma4(acc[0], a0.x, xv); fma4(acc[1], a0.y, xv);
                fma4(acc[2], a0.z, xv); fma4(acc[3], a0.w, xv);
                fma4(acc[4], a1.x, xv); fma4(acc[5], a1.y, xv);
                fma4(acc[6], a1.z, xv); fma4(acc[7], a1.w, xv);
            }
        }
        __syncthreads();
    }

    // ---- final: reduce over 16 row-groups via xt, two k-halves
    float4* og = (float4*)(out + (size_t)b * (KQ * DQ));
    #pragma unroll
    for (int half = 0; half < 2; ++half) {
        #pragma unroll
        for (int kk = 0; kk < 4; ++kk) xt[(kk * 16 + rg) * 16 + qd] = acc[half * 4 + kk];
        __syncthreads();
        if (t < 64) {
            const int kk = t >> 4, q = t & 15;
            float4 sum = make_float4(0.f, 0.f, 0.f, 0.f);
            #pragma unroll
            for (int g = 0; g < 16; ++g) add4(sum, xt[(kk * 16 + g) * 16 + q]);
            og[(half * 4 + kk) * 16 + q] = sum;
        }
        __syncthreads();
    }
}

extern "C" void kernel_launch(void* const* d_in, const int* in_sizes, int n_in,
                              void* d_out, int out_size, void* d_ws, size_t ws_size,
                              hipStream_t stream) {
    const float* x     = (const float*)d_in[0];   // [B, L, D] fp32
    const float* proto = (const float*)d_in[1];   // [K, D] fp32
    float* out = (float*)d_out;                   // [B, K, D] fp32
    float* pn  = (float*)d_ws;                    // normalized prototype (2 KB)

    const int Bn = in_sizes[0] / (LQ * DQ);       // 4096

    proto_norm_kernel<<<1, 64, 0, stream>>>(proto, pn);
    projector_kernel<<<Bn, 256, 0, stream>>>(x, pn, out);
}

// Round 5
// 55.729 us; speedup vs baseline: 2.6792x; 1.0689x over previous
//
#include <hip/hip_runtime.h>

// Projector: out[b,k,d] = sum_l softmax_k( cos(p_k, x[b,l]) ) * x[b,l,d]
// B=4096, L=200, D=64, K=8, fp32.
// v5: LDS-issue-pipe was the bottleneck (~52 DS instrs/wave-tile ~= 53us/CU).
// Now: dots from registers during staging (p-hat in 64 VGPR, loaded+normalized
// once per block), octet butterfly reduce (DPP + ds_swizzle), rotation-swizzled
// x tile (conflict-free stage writes AND ph2 reads), k-in-thread accumulate.
// ~24 DS instrs/wave-tile. Proto-norm fused (no second kernel).

#define LQ 200
#define DQ 64
#define KQ 8
#define TR 64
#define NT 4
#define XTQ (TR * 16)    // 1024 float4 = 16 KB
#define SAS 12           // sA row stride (dwords): 48 B -> b128-aligned, ~2-way banks

__device__ __forceinline__ float dppx1(float v) {   // lane ^ 1 (quad_perm [1,0,3,2])
    return __int_as_float(__builtin_amdgcn_update_dpp(0, __float_as_int(v), 0xB1, 0xF, 0xF, true));
}
__device__ __forceinline__ float dppx2(float v) {   // lane ^ 2 (quad_perm [2,3,0,1])
    return __int_as_float(__builtin_amdgcn_update_dpp(0, __float_as_int(v), 0x4E, 0xF, 0xF, true));
}
__device__ __forceinline__ float swz4(float v) {    // lane ^ 4 (ds_swizzle BitMode)
    return __int_as_float(__builtin_amdgcn_ds_swizzle(__float_as_int(v), 0x101F));
}
__device__ __forceinline__ float allred8(float v) { // all-reduce over octet (t&7)
    v += dppx1(v); v += dppx2(v); v += swz4(v); return v;
}
__device__ __forceinline__ float dot4f(float4 a, float4 b) {
    return a.x * b.x + a.y * b.y + a.z * b.z + a.w * b.w;
}
__device__ __forceinline__ void fma4(float4& acc, float a, float4 v) {
    acc.x += a * v.x; acc.y += a * v.y; acc.z += a * v.z; acc.w += a * v.w;
}
__device__ __forceinline__ void add4(float4& acc, float4 v) {
    acc.x += v.x; acc.y += v.y; acc.z += v.z; acc.w += v.w;
}
__device__ __forceinline__ void mul4(float4& a, float s) {
    a.x *= s; a.y *= s; a.z *= s; a.w *= s;
}

// split butterfly over the 8 octet-lanes: s[8] = this lane's chunk-partials for
// all 8 k. Returns the full dot for k == (t&7). (verified in v3)
__device__ __forceinline__ float reduce_dots(const float* s, bool b1, bool b2, bool b3) {
    float T0 = (b1 ? s[1] : s[0]) + dppx1(b1 ? s[0] : s[1]);
    float T1 = (b1 ? s[3] : s[2]) + dppx1(b1 ? s[2] : s[3]);
    float T2 = (b1 ? s[5] : s[4]) + dppx1(b1 ? s[4] : s[5]);
    float T3 = (b1 ? s[7] : s[6]) + dppx1(b1 ? s[6] : s[7]);
    float K0 = (b2 ? T1 : T0) + dppx2(b2 ? T0 : T1);
    float K1 = (b2 ? T3 : T2) + dppx2(b2 ? T2 : T3);
    return (b3 ? K1 : K0) + swz4(b3 ? K0 : K1);
}

__global__ __launch_bounds__(256, 3) void projector_kernel(const float* __restrict__ x,
                                                           const float* __restrict__ proto,
                                                           float* __restrict__ out) {
    __shared__ __align__(16) float4 xt[XTQ];        // 16 KB rotation-swizzled x tile
    __shared__ __align__(16) float  sA[TR * SAS];   // 3 KB attn [row][k]

    const int b = blockIdx.x;
    const int t = threadIdx.x;

    // ph1 mapping: octet lane c = chunk (8 floats) and final k; rp = row-pair
    const int c  = t & 7;
    const int rp = t >> 3;            // 0..31
    const int r0 = 2 * rp, r1 = r0 + 1;
    const bool s1b = (c & 1) != 0;
    const bool s2b = (c & 2) != 0;
    const bool s3b = (c & 4) != 0;

    // ph2 mapping: d-quad qd, row-group rg (4 rows)
    const int qd = t & 15;
    const int rg = t >> 4;            // 0..15

    // ---- p-hat: load + normalize in registers (once; octet-redundant)
    float4 phA[KQ], phB[KQ];
    {
        const float4* p4 = (const float4*)proto;
        #pragma unroll
        for (int k = 0; k < KQ; ++k) {
            phA[k] = p4[k * 16 + 2 * c];
            phB[k] = p4[k * 16 + 2 * c + 1];
        }
        #pragma unroll
        for (int k = 0; k < KQ; ++k) {
            float sq = allred8(dot4f(phA[k], phA[k]) + dot4f(phB[k], phB[k]));
            float rn = __frsqrt_rn(fmaxf(sq, 1e-12f));
            mul4(phA[k], rn); mul4(phB[k], rn);
        }
    }

    const float4* xb4 = (const float4*)(x + (size_t)b * (LQ * DQ));

    // tile-0 staged registers: rows r0,r1 x chunk c (2x 32B contiguous per row)
    float4 pxA0 = xb4[r0 * 16 + 2 * c], pxA1 = xb4[r0 * 16 + 2 * c + 1];
    float4 pxB0 = xb4[r1 * 16 + 2 * c], pxB1 = xb4[r1 * 16 + 2 * c + 1];

    float4 acc[KQ];
    #pragma unroll
    for (int k = 0; k < KQ; ++k) acc[k] = make_float4(0.f, 0.f, 0.f, 0.f);

    #pragma unroll
    for (int ti = 0; ti < NT; ++ti) {
        const int nr = (ti == NT - 1) ? (LQ - (NT - 1) * TR) : TR;   // compile-time

        // ---- stage px -> xt, phys_quad = (logical_q + rp) & 15 (conflict-free)
        if (r0 < nr) {
            xt[(r0 << 4) | ((2 * c + rp) & 15)]     = pxA0;
            xt[(r0 << 4) | ((2 * c + 1 + rp) & 15)] = pxA1;
            xt[(r1 << 4) | ((2 * c + rp) & 15)]     = pxB0;
            xt[(r1 << 4) | ((2 * c + 1 + rp) & 15)] = pxB1;
        }

        // ---- T14: issue next tile's loads now (consumed at next stage)
        float4 nA0 = pxA0, nA1 = pxA1, nB0 = pxB0, nB1 = pxB1;
        if (ti + 1 < NT) {
            const int nrn = (ti + 1 == NT - 1) ? (LQ - (NT - 1) * TR) : TR;
            if (r0 < nrn) {
                const float4* src = xb4 + (ti + 1) * XTQ;
                nA0 = src[r0 * 16 + 2 * c]; nA1 = src[r0 * 16 + 2 * c + 1];
                nB0 = src[r1 * 16 + 2 * c]; nB1 = src[r1 * 16 + 2 * c + 1];
            }
        }

        // ---- dots from registers; octet butterfly; in-register softmax
        if (r0 < nr) {
            float s0[KQ];
            #pragma unroll
            for (int k = 0; k < KQ; ++k)
                s0[k] = dot4f(pxA0, phA[k]) + dot4f(pxA1, phB[k]);
            float d0 = reduce_dots(s0, s1b, s2b, s3b);     // full dot, row r0, k=c

            float s1[KQ];
            #pragma unroll
            for (int k = 0; k < KQ; ++k)
                s1[k] = dot4f(pxB0, phA[k]) + dot4f(pxB1, phB[k]);
            float d1 = reduce_dots(s1, s1b, s2b, s3b);     // row r1

            float sq0 = allred8(dot4f(pxA0, pxA0) + dot4f(pxA1, pxA1));
            float sq1 = allred8(dot4f(pxB0, pxB0) + dot4f(pxB1, pxB1));

            float e0 = __expf(d0 * __frsqrt_rn(fmaxf(sq0, 1e-12f)));
            float e1 = __expf(d1 * __frsqrt_rn(fmaxf(sq1, 1e-12f)));
            float den0 = allred8(e0);
            float den1 = allred8(e1);
            sA[r0 * SAS + c] = e0 * __frcp_rn(den0);
            sA[r1 * SAS + c] = e1 * __frcp_rn(den1);
        }
        __syncthreads();

        // ---- ph2: acc[k] += attn[row][k] * x[row][d-quad] (x read exactly once)
        #pragma unroll
        for (int i = 0; i < 4; ++i) {
            const int row = rg * 4 + i;
            if (row < nr) {
                float4 xv = xt[(row << 4) | ((qd + (row >> 1)) & 15)];
                float4 a0 = *(const float4*)&sA[row * SAS];
                float4 a1 = *(const float4*)&sA[row * SAS + 4];
                fma4(acc[0], a0.x, xv); fma4(acc[1], a0.y, xv);
                fma4(acc[2], a0.z, xv); fma4(acc[3], a0.w, xv);
                fma4(acc[4], a1.x, xv); fma4(acc[5], a1.y, xv);
                fma4(acc[6], a1.z, xv); fma4(acc[7], a1.w, xv);
            }
        }
        __syncthreads();

        pxA0 = nA0; pxA1 = nA1; pxB0 = nB0; pxB1 = nB1;
    }

    // ---- final: reduce over the 16 row-groups via xt scratch, two k-halves
    float4* og = (float4*)(out + (size_t)b * (KQ * DQ));
    #pragma unroll
    for (int half = 0; half < 2; ++half) {
        #pragma unroll
        for (int kk = 0; kk < 4; ++kk) xt[(kk * 16 + rg) * 16 + qd] = acc[half * 4 + kk];
        __syncthreads();
        if (t < 64) {
            const int kk = t >> 4, q = t & 15;
            float4 sum = make_float4(0.f, 0.f, 0.f, 0.f);
            #pragma unroll
            for (int g = 0; g < 16; ++g) add4(sum, xt[(kk * 16 + g) * 16 + q]);
            og[(half * 4 + kk) * 16 + q] = sum;
        }
        __syncthreads();
    }
}

extern "C" void kernel_launch(void* const* d_in, const int* in_sizes, int n_in,
                              void* d_out, int out_size, void* d_ws, size_t ws_size,
                              hipStream_t stream) {
    const float* x     = (const float*)d_in[0];   // [B, L, D] fp32
    const float* proto = (const float*)d_in[1];   // [K, D] fp32
    float* out = (float*)d_out;                   // [B, K, D] fp32

    const int Bn = in_sizes[0] / (LQ * DQ);       // 4096

    projector_kernel<<<Bn, 256, 0, stream>>>(x, proto, out);
}